// Round 1
// baseline (527.964 us; speedup 1.0000x reference)
//
#include <hip/hip_runtime.h>
#include <hip/hip_bf16.h>

#define BIGF 1e30f
#define TC 80   // channels
#define TN 512  // sequence length (N == M)

// ---------------------------------------------------------------------------
// Kernel 1: pairwise squared distances (unchanged).
// NOTE: launched with (y, x) swapped so the output buffer holds the
// TRANSPOSED distance matrix D'[b][j][i] = ||x_i - y_j||^2. FP add/mul
// commutativity makes the values bitwise identical to D[b][i][j].
// ---------------------------------------------------------------------------
__global__ __launch_bounds__(256) void pairdist_kernel(
    const float* __restrict__ x, const float* __restrict__ y,
    float* __restrict__ D) {
  const int b  = blockIdx.z;
  const int n0 = blockIdx.x * 64;
  const int m0 = blockIdx.y * 64;

  __shared__ float xs[TC][64];
  __shared__ float ys[TC][64];
  __shared__ float xxs[64];
  __shared__ float yys[64];

  const float* xb = x + (size_t)b * TC * TN;
  const float* yb = y + (size_t)b * TC * TN;
  const int tid = threadIdx.x;

  for (int idx = tid; idx < TC * 64; idx += 256) {
    int c = idx >> 6, n = idx & 63;
    xs[c][n] = xb[c * TN + n0 + n];
    ys[c][n] = yb[c * TN + m0 + n];
  }
  __syncthreads();

  if (tid < 64) {
    float s = 0.f;
    for (int c = 0; c < TC; ++c) { float v = xs[c][tid]; s += v * v; }
    xxs[tid] = s;
  } else if (tid < 128) {
    int t2 = tid - 64;
    float s = 0.f;
    for (int c = 0; c < TC; ++c) { float v = ys[c][t2]; s += v * v; }
    yys[t2] = s;
  }
  __syncthreads();

  const int tm = tid & 15, tn = tid >> 4;
  float acc[4][4] = {};
  for (int c = 0; c < TC; ++c) {
    float4 xa = *(const float4*)&xs[c][tn * 4];
    float4 ya = *(const float4*)&ys[c][tm * 4];
    float xv[4] = {xa.x, xa.y, xa.z, xa.w};
    float yv[4] = {ya.x, ya.y, ya.z, ya.w};
#pragma unroll
    for (int a = 0; a < 4; ++a)
#pragma unroll
      for (int q = 0; q < 4; ++q) acc[a][q] += xv[a] * yv[q];
  }

  float* Dbase = D + (size_t)b * TN * TN;
#pragma unroll
  for (int a = 0; a < 4; ++a) {
    int n = n0 + tn * 4 + a;
    float xxv = xxs[tn * 4 + a];
    float4 o;
    o.x = xxv + yys[tm * 4 + 0] - 2.f * acc[a][0];
    o.y = xxv + yys[tm * 4 + 1] - 2.f * acc[a][1];
    o.z = xxv + yys[tm * 4 + 2] - 2.f * acc[a][2];
    o.w = xxv + yys[tm * 4 + 3] - 2.f * acc[a][3];
    *(float4*)&Dbase[(size_t)n * TN + m0 + tm * 4] = o;
  }
}

// ---------------------------------------------------------------------------
// Kernel 2: soft-DTW, single-wave slab sweep. One block = one wave64 per
// batch. Lane t owns DP rows 8t+1..8t+8 (values in registers). At iteration
// s, lane t processes column j = s - t + 1 for all 8 of its rows (sequential
// softmin chain in registers). The only cross-lane dependency is the bottom
// row value, passed via one __shfl_up per iteration: lane t-1 computes
// R[8t][j] at iteration s-1, lane t consumes it at iteration s.
// No __syncthreads, no LDS.
//
// Boundary trick: with all three softmin inputs == 1e30f, the cell computes
// 1e30 + (d - log 3) which rounds to exactly 1e30f, so pre-start lanes
// self-sustain the BIG boundary bitwise — no validity mask needed.
//
// D is consumed from the TRANSPOSED layout D'[j][i]: lane t's 8 values for
// column j are 8 contiguous floats -> two float4 loads, prefetched one
// iteration ahead.
// ---------------------------------------------------------------------------
__global__ __launch_bounds__(64) void sdtw_kernel(
    const float* __restrict__ Dt, float* __restrict__ out) {
  const int b = blockIdx.x;
  const int t = threadIdx.x;          // lane, owns rows 8t+1..8t+8
  const float* Db = Dt + (size_t)b * TN * TN;
  const int i0 = t * 8;

  float prev[8];                      // R[i][j-1] for own 8 rows
#pragma unroll
  for (int r = 0; r < 8; ++r) prev[r] = BIGF;   // R[i][0] = BIG
  float up_cur  = BIGF;               // R[8t][j]   (row above slab, col j)
  float up_prev = (t == 0) ? 0.f : BIGF;  // R[8t][j-1]; R[0][0] = 0

  auto clampi = [](int v) { return v < 0 ? 0 : (v > TN - 1 ? TN - 1 : v); };

  // dA/dB hold D'[s-t][i0..i0+7] for the current iteration.
  const float* rp = Db + (size_t)clampi(0 - t) * TN + i0;
  float4 dA = *(const float4*)rp;
  float4 dB = *(const float4*)(rp + 4);

  for (int s = 0; s < TN + 63; ++s) {
    // Prefetch next column's 8 D-values (clamped; garbage cols feed only
    // BIG-saturated pre/post-range cells).
    const float* np = Db + (size_t)clampi(s + 1 - t) * TN + i0;
    float4 nA = *(const float4*)np;
    float4 nB = *(const float4*)(np + 4);

    float r0 = up_prev;               // R[i-1][j-1]
    float r1 = up_cur;                // R[i-1][j]
    float dv[8] = {dA.x, dA.y, dA.z, dA.w, dB.x, dB.y, dB.z, dB.w};
#pragma unroll
    for (int r = 0; r < 8; ++r) {
      float r2 = prev[r];             // R[i][j-1]
      float m3 = fminf(fminf(r0, r1), r2);
      float ss = __expf(m3 - r0) + __expf(m3 - r1) + __expf(m3 - r2);
      float cur = dv[r] + (m3 - __logf(ss));
      r0 = r2;                        // diag input for next row down
      prev[r] = cur;
      r1 = cur;                       // row-above input for next row down
    }

    up_prev = up_cur;
    float sh = __shfl_up(prev[7], 1, 64);
    up_cur = (t == 0) ? BIGF : sh;    // R[0][j] = BIG for j >= 1
    dA = nA; dB = nB;
  }

  if (t == 63) out[b] = prev[7];      // R[512][512]
}

extern "C" void kernel_launch(void* const* d_in, const int* in_sizes, int n_in,
                              void* d_out, int out_size, void* d_ws, size_t ws_size,
                              hipStream_t stream) {
  const float* x = (const float*)d_in[0];
  const float* y = (const float*)d_in[1];
  float* out = (float*)d_out;
  float* D = (float*)d_ws;  // 32*512*512*4 = 33.5 MB, holds D' (transposed)

  dim3 g1(TN / 64, TN / 64, 32);
  // Swapped args -> buffer holds D'[b][j][i] (bitwise equal to D^T).
  pairdist_kernel<<<g1, 256, 0, stream>>>(y, x, D);
  sdtw_kernel<<<32, 64, 0, stream>>>(D, out);
}

// Round 2
// 517.378 us; speedup vs baseline: 1.0205x; 1.0205x over previous
//
#include <hip/hip_runtime.h>
#include <hip/hip_bf16.h>

#define BIGF 1e30f
#define TC 80   // channels
#define TN 512  // sequence length (N == M)

// ---------------------------------------------------------------------------
// Kernel 1: pairwise squared distances (unchanged).
// Launched with (y, x) swapped so the buffer holds the TRANSPOSED matrix
// D'[b][j][i] = ||x_i - y_j||^2 (bitwise equal to D^T by FP commutativity).
// ---------------------------------------------------------------------------
__global__ __launch_bounds__(256) void pairdist_kernel(
    const float* __restrict__ x, const float* __restrict__ y,
    float* __restrict__ D) {
  const int b  = blockIdx.z;
  const int n0 = blockIdx.x * 64;
  const int m0 = blockIdx.y * 64;

  __shared__ float xs[TC][64];
  __shared__ float ys[TC][64];
  __shared__ float xxs[64];
  __shared__ float yys[64];

  const float* xb = x + (size_t)b * TC * TN;
  const float* yb = y + (size_t)b * TC * TN;
  const int tid = threadIdx.x;

  for (int idx = tid; idx < TC * 64; idx += 256) {
    int c = idx >> 6, n = idx & 63;
    xs[c][n] = xb[c * TN + n0 + n];
    ys[c][n] = yb[c * TN + m0 + n];
  }
  __syncthreads();

  if (tid < 64) {
    float s = 0.f;
    for (int c = 0; c < TC; ++c) { float v = xs[c][tid]; s += v * v; }
    xxs[tid] = s;
  } else if (tid < 128) {
    int t2 = tid - 64;
    float s = 0.f;
    for (int c = 0; c < TC; ++c) { float v = ys[c][t2]; s += v * v; }
    yys[t2] = s;
  }
  __syncthreads();

  const int tm = tid & 15, tn = tid >> 4;
  float acc[4][4] = {};
  for (int c = 0; c < TC; ++c) {
    float4 xa = *(const float4*)&xs[c][tn * 4];
    float4 ya = *(const float4*)&ys[c][tm * 4];
    float xv[4] = {xa.x, xa.y, xa.z, xa.w};
    float yv[4] = {ya.x, ya.y, ya.z, ya.w};
#pragma unroll
    for (int a = 0; a < 4; ++a)
#pragma unroll
      for (int q = 0; q < 4; ++q) acc[a][q] += xv[a] * yv[q];
  }

  float* Dbase = D + (size_t)b * TN * TN;
#pragma unroll
  for (int a = 0; a < 4; ++a) {
    int n = n0 + tn * 4 + a;
    float xxv = xxs[tn * 4 + a];
    float4 o;
    o.x = xxv + yys[tm * 4 + 0] - 2.f * acc[a][0];
    o.y = xxv + yys[tm * 4 + 1] - 2.f * acc[a][1];
    o.z = xxv + yys[tm * 4 + 2] - 2.f * acc[a][2];
    o.w = xxv + yys[tm * 4 + 3] - 2.f * acc[a][3];
    *(float4*)&Dbase[(size_t)n * TN + m0 + tm * 4] = o;
  }
}

// ---------------------------------------------------------------------------
// Kernel 2: soft-DTW single-wave slab sweep, PREFETCH DEPTH 4.
// One block = one wave64 per batch. Lane t owns DP rows 8t+1..8t+8 in
// registers; at iteration s it processes column j = s-t+1. Cross-lane dep =
// bottom row value via one __shfl_up per iteration. No barriers, no LDS.
//
// Round-1 lesson: 1-deep prefetch left ~1200 cy/iter of exposed global-load
// latency (1 wave/CU, zero TLP). Now loads for iteration s+4 are issued at
// iteration s into STATICALLY NAMED ring buffers (runtime-indexed arrays
// would spill to scratch), keeping 8 loads in flight; 4 iters x ~500 cy of
// chain covers ~900 cy of HBM latency.
//
// Boundary: with all softmin inputs == 1e30f the cell yields exactly 1e30f
// (log3 and dv are below ulp(1e30)=7.5e22), so pre-range cells self-sustain
// BIG bitwise; post-range garbage only ever flows into columns > 512 of the
// next lane. Iteration count is EXACTLY 575 (s=574 computes lane63/col512);
// a 576th iteration would corrupt the answer -> 143x4 unrolled + 3 peeled.
// ---------------------------------------------------------------------------
__global__ __launch_bounds__(64) void sdtw_kernel(
    const float* __restrict__ Dt, float* __restrict__ out) {
  const int b = blockIdx.x;
  const int t = threadIdx.x;          // lane, owns rows 8t+1..8t+8
  const float* Db = Dt + (size_t)b * TN * TN;
  const int i0 = t * 8;

  float prev[8];                      // R[i][j-1] for own 8 rows
#pragma unroll
  for (int r = 0; r < 8; ++r) prev[r] = BIGF;
  float up_cur  = BIGF;               // R[8t][j]
  float up_prev = (t == 0) ? 0.f : BIGF;  // R[8t][j-1]; R[0][0]=0

  // Pointer to D'[clamp(s-t)][i0] — row consumed at iteration s.
  auto rowp = [&](int s) -> const float* {
    int v = s - t;
    v = v < 0 ? 0 : (v > TN - 1 ? TN - 1 : v);
    return Db + (size_t)v * TN + i0;
  };

  // Preamble: fill 4-deep ring (iterations 0..3).
  const float* p0 = rowp(0);
  float4 b0A = *(const float4*)p0, b0B = *(const float4*)(p0 + 4);
  const float* p1 = rowp(1);
  float4 b1A = *(const float4*)p1, b1B = *(const float4*)(p1 + 4);
  const float* p2 = rowp(2);
  float4 b2A = *(const float4*)p2, b2B = *(const float4*)(p2 + 4);
  const float* p3 = rowp(3);
  float4 b3A = *(const float4*)p3, b3B = *(const float4*)(p3 + 4);

  auto body = [&](int s, float4& bA, float4& bB) {
    // Consume this iteration's D values, then immediately reuse the buffer
    // for the s+4 prefetch (independent of the chain -> scheduled early).
    float dv[8] = {bA.x, bA.y, bA.z, bA.w, bB.x, bB.y, bB.z, bB.w};
    const float* np = rowp(s + 4);
    bA = *(const float4*)np;
    bB = *(const float4*)(np + 4);

    float r0 = up_prev;               // R[i-1][j-1]
    float r1 = up_cur;                // R[i-1][j]
#pragma unroll
    for (int r = 0; r < 8; ++r) {
      float r2 = prev[r];             // R[i][j-1]
      float m3 = fminf(fminf(r0, r1), r2);
      float ss = __expf(m3 - r0) + __expf(m3 - r1) + __expf(m3 - r2);
      float cur = dv[r] + (m3 - __logf(ss));
      r0 = r2;
      prev[r] = cur;
      r1 = cur;
    }
    up_prev = up_cur;
    float sh = __shfl_up(prev[7], 1, 64);
    up_cur = (t == 0) ? BIGF : sh;    // R[0][j] = BIG for j >= 1
  };

  // 575 total iterations: 143 x 4 unrolled + 3 peeled.
  for (int s = 0; s < 572; s += 4) {
    body(s + 0, b0A, b0B);
    body(s + 1, b1A, b1B);
    body(s + 2, b2A, b2B);
    body(s + 3, b3A, b3B);
  }
  body(572, b0A, b0B);
  body(573, b1A, b1B);
  body(574, b2A, b2B);

  if (t == 63) out[b] = prev[7];      // R[512][512]
}

extern "C" void kernel_launch(void* const* d_in, const int* in_sizes, int n_in,
                              void* d_out, int out_size, void* d_ws, size_t ws_size,
                              hipStream_t stream) {
  const float* x = (const float*)d_in[0];
  const float* y = (const float*)d_in[1];
  float* out = (float*)d_out;
  float* D = (float*)d_ws;  // 32*512*512*4 = 33.5 MB, holds D' (transposed)

  dim3 g1(TN / 64, TN / 64, 32);
  // Swapped args -> buffer holds D'[b][j][i] (bitwise equal to D^T).
  pairdist_kernel<<<g1, 256, 0, stream>>>(y, x, D);
  sdtw_kernel<<<32, 64, 0, stream>>>(D, out);
}

// Round 4
// 401.081 us; speedup vs baseline: 1.3164x; 1.2900x over previous
//
#include <hip/hip_runtime.h>
#include <hip/hip_bf16.h>

#define BIGF 1e30f
#define TC 80   // channels
#define TN 512  // sequence length (N == M)

typedef float f32x4 __attribute__((ext_vector_type(4)));
typedef __attribute__((address_space(1))) const unsigned int gu32;
typedef __attribute__((address_space(3))) unsigned int lu32;

// ---------------------------------------------------------------------------
// Kernel 1: pairwise squared distances (unchanged).
// Launched with (y, x) swapped so the buffer holds the TRANSPOSED matrix
// D'[b][j][i] = ||x_i - y_j||^2 (bitwise equal to D^T by FP commutativity).
// ---------------------------------------------------------------------------
__global__ __launch_bounds__(256) void pairdist_kernel(
    const float* __restrict__ x, const float* __restrict__ y,
    float* __restrict__ D) {
  const int b  = blockIdx.z;
  const int n0 = blockIdx.x * 64;
  const int m0 = blockIdx.y * 64;

  __shared__ float xs[TC][64];
  __shared__ float ys[TC][64];
  __shared__ float xxs[64];
  __shared__ float yys[64];

  const float* xb = x + (size_t)b * TC * TN;
  const float* yb = y + (size_t)b * TC * TN;
  const int tid = threadIdx.x;

  for (int idx = tid; idx < TC * 64; idx += 256) {
    int c = idx >> 6, n = idx & 63;
    xs[c][n] = xb[c * TN + n0 + n];
    ys[c][n] = yb[c * TN + m0 + n];
  }
  __syncthreads();

  if (tid < 64) {
    float s = 0.f;
    for (int c = 0; c < TC; ++c) { float v = xs[c][tid]; s += v * v; }
    xxs[tid] = s;
  } else if (tid < 128) {
    int t2 = tid - 64;
    float s = 0.f;
    for (int c = 0; c < TC; ++c) { float v = ys[c][t2]; s += v * v; }
    yys[t2] = s;
  }
  __syncthreads();

  const int tm = tid & 15, tn = tid >> 4;
  float acc[4][4] = {};
  for (int c = 0; c < TC; ++c) {
    float4 xa = *(const float4*)&xs[c][tn * 4];
    float4 ya = *(const float4*)&ys[c][tm * 4];
    float xv[4] = {xa.x, xa.y, xa.z, xa.w};
    float yv[4] = {ya.x, ya.y, ya.z, ya.w};
#pragma unroll
    for (int a = 0; a < 4; ++a)
#pragma unroll
      for (int q = 0; q < 4; ++q) acc[a][q] += xv[a] * yv[q];
  }

  float* Dbase = D + (size_t)b * TN * TN;
#pragma unroll
  for (int a = 0; a < 4; ++a) {
    int n = n0 + tn * 4 + a;
    float xxv = xxs[tn * 4 + a];
    float4 o;
    o.x = xxv + yys[tm * 4 + 0] - 2.f * acc[a][0];
    o.y = xxv + yys[tm * 4 + 1] - 2.f * acc[a][1];
    o.z = xxv + yys[tm * 4 + 2] - 2.f * acc[a][2];
    o.w = xxv + yys[tm * 4 + 3] - 2.f * acc[a][3];
    *(float4*)&Dbase[(size_t)n * TN + m0 + tm * 4] = o;
  }
}

// ---------------------------------------------------------------------------
// Kernel 2: soft-DTW single-wave slab sweep, LDS-RING PREFETCH (depth 8).
//
// Round-3 post-mortem: keeping ASYNC load results in C-visible registers is
// unsound — ring buffers are loop-carried PHIs and the allocator inserted
// copies of registers whose loads were still in flight -> NaN. Fix: pending
// state lives in an 8-slot LDS ring filled by global_load_lds (per-lane
// global source address, uniform LDS base + lane*16). Nothing for the
// allocator to copy. Counted `s_waitcnt vmcnt(14)` gates slot readiness;
// the LDS->reg read is one asm block CONTAINING its own lgkmcnt(0), so its
// outputs are complete values at asm exit (no hoisting hazard, rule #18
// does not apply). __shfl_up replaced by pure-VALU DPP wave_shr:1 with
// old=BIG (bit-identical to shfl_up + lane0 select) so the loop has zero
// compiler-visible DS ops to attract conservative waits vs the LDS DMA.
//
// vmcnt invariant: preamble issues 8 slots x 2 DMA ops = 16 outstanding.
// Each body: wait vmcnt(14) [oldest slot landed] -> ds_read it -> refill it
// (2 ops, back to 16) -> softmin chain -> DPP. Exactly 575 iterations
// (71 x 8 + 7 peeled); DP math untouched from the absmax-0.0 version.
// ---------------------------------------------------------------------------
__global__ __launch_bounds__(64) __attribute__((amdgpu_waves_per_eu(1)))
void sdtw_kernel(const float* __restrict__ Dt, float* __restrict__ out) {
  const int b = blockIdx.x;
  const int t = threadIdx.x;          // lane, owns rows 8t+1..8t+8
  const float* Db = Dt + (size_t)b * TN * TN;
  const int i0 = t * 8;

  __shared__ float ring[8][512];      // 8 slots x 2 KB (lane-major 16B units)

  float prev[8];                      // R[i][j-1] for own 8 rows
#pragma unroll
  for (int r = 0; r < 8; ++r) prev[r] = BIGF;
  float up_cur  = BIGF;               // R[8t][j]
  float up_prev = (t == 0) ? 0.f : BIGF;  // R[8t][j-1]; R[0][0]=0

  // Per-lane global pointer to D'[clamp(s-t)][i0] (row consumed at iter s).
  auto rowp = [&](int s) -> const float* {
    int v = s - t;
    v = v < 0 ? 0 : (v > TN - 1 ? TN - 1 : v);
    return Db + (size_t)v * TN + i0;
  };

  // Stage iter-s data into slot: lane t's 8 floats -> ring[slot][lane-major].
  auto stage = [&](int slot, const float* gp) {
    __builtin_amdgcn_global_load_lds((gu32*)gp,       (lu32*)&ring[slot][0],
                                     16, 0, 0);
    __builtin_amdgcn_global_load_lds((gu32*)(gp + 4), (lu32*)&ring[slot][256],
                                     16, 0, 0);
  };

  // 32-bit LDS byte offset of the ring base (AS(3) pointers are 32-bit).
  const unsigned lbase =
      (unsigned)(size_t)(__attribute__((address_space(3))) float*)&ring[0][0];

  // Preamble: fill all 8 slots (iters 0..7) -> 16 outstanding DMA ops.
  stage(0, rowp(0)); stage(1, rowp(1)); stage(2, rowp(2)); stage(3, rowp(3));
  stage(4, rowp(4)); stage(5, rowp(5)); stage(6, rowp(6)); stage(7, rowp(7));

  auto body = [&](int s, int slot) {
    // Oldest slot's 2 DMA writes have landed in LDS.
    asm volatile("s_waitcnt vmcnt(14)" ::: "memory");

    // Read this lane's 8 D-values; lgkmcnt(0) INSIDE the asm -> outputs are
    // complete values at asm exit (safe against any reordering).
    f32x4 cA, cB;
    unsigned a = lbase + (unsigned)(slot * 2048) + (unsigned)(t * 16);
    asm volatile("ds_read_b128 %0, %2\n\t"
                 "ds_read_b128 %1, %2 offset:1024\n\t"
                 "s_waitcnt lgkmcnt(0)"
                 : "=&v"(cA), "=&v"(cB)
                 : "v"(a)
                 : "memory");

    // Refill this slot for iteration s+8 (DMA write lands well after the
    // ds_read above completed; clamped rows -> always valid memory).
    stage(slot, rowp(s + 8));

    float dv[8] = {cA[0], cA[1], cA[2], cA[3], cB[0], cB[1], cB[2], cB[3]};
    float r0 = up_prev;               // R[i-1][j-1]
    float r1 = up_cur;                // R[i-1][j]
#pragma unroll
    for (int r = 0; r < 8; ++r) {
      float r2 = prev[r];             // R[i][j-1]
      float m3 = fminf(fminf(r0, r1), r2);
      float ss = __expf(m3 - r0) + __expf(m3 - r1) + __expf(m3 - r2);
      float cur = dv[r] + (m3 - __logf(ss));
      r0 = r2;
      prev[r] = cur;
      r1 = cur;
    }
    up_prev = up_cur;
    // prev[7] shifted up one lane; lane 0 receives BIG (== old operand).
    // Pure VALU (v_mov_b32_dpp wave_shr:1) — identical to shfl_up + select.
    int sh = __builtin_amdgcn_update_dpp(
        __float_as_int(BIGF), __float_as_int(prev[7]), 0x138, 0xf, 0xf, false);
    up_cur = __int_as_float(sh);
  };

  // 575 total iterations: 71 x 8 unrolled + 7 peeled.
  for (int s = 0; s < 568; s += 8) {
    body(s + 0, 0); body(s + 1, 1); body(s + 2, 2); body(s + 3, 3);
    body(s + 4, 4); body(s + 5, 5); body(s + 6, 6); body(s + 7, 7);
  }
  body(568, 0); body(569, 1); body(570, 2); body(571, 3);
  body(572, 4); body(573, 5); body(574, 6);

  // Drain remaining speculative DMA before wave exit.
  asm volatile("s_waitcnt vmcnt(0)" ::: "memory");
  if (t == 63) out[b] = prev[7];      // R[512][512]
}

extern "C" void kernel_launch(void* const* d_in, const int* in_sizes, int n_in,
                              void* d_out, int out_size, void* d_ws, size_t ws_size,
                              hipStream_t stream) {
  const float* x = (const float*)d_in[0];
  const float* y = (const float*)d_in[1];
  float* out = (float*)d_out;
  float* D = (float*)d_ws;  // 32*512*512*4 = 33.5 MB, holds D' (transposed)

  dim3 g1(TN / 64, TN / 64, 32);
  // Swapped args -> buffer holds D'[b][j][i] (bitwise equal to D^T).
  pairdist_kernel<<<g1, 256, 0, stream>>>(y, x, D);
  sdtw_kernel<<<32, 64, 0, stream>>>(D, out);
}

// Round 5
// 266.399 us; speedup vs baseline: 1.9819x; 1.5056x over previous
//
#include <hip/hip_runtime.h>
#include <hip/hip_bf16.h>

#define BIGF 1e30f
#define TC 80   // channels
#define TN 512  // sequence length (N == M)
#define L2E 1.4426950408889634f   // log2(e)
#define LN2 0.6931471805599453f   // 1/log2(e)

typedef float f32x4 __attribute__((ext_vector_type(4)));
typedef __attribute__((address_space(1))) const unsigned int gu32;
typedef __attribute__((address_space(3))) unsigned int lu32;

// ---------------------------------------------------------------------------
// Kernel 1: pairwise squared distances, written in the SKEWED layout that
// kernel 2's slab sweep consumes contiguously, pre-scaled by log2(e).
//
// Logical: D'[j][i] = ||x_i - y_j||^2 (computed by calling with (y,x)
// swapped; FP commutativity keeps values bitwise equal to D^T).
// Storage:  E[p][t*8 + w],  t = i>>3, w = i&7, s = j + t, p = s & 511.
// The map (j,i) -> (p, t, w) is a bijection into 512x512 floats per batch:
// logical skew-rows s and s+512 use disjoint lane sets {t <= p} / {t > p},
// so the mod-512 overlay never collides. Same 33.5 MB footprint as D.
// At sweep iteration s (63 <= s <= 511), all 64 lanes' data = row p = s:
// one contiguous 2 KB line-sequential block.
// ---------------------------------------------------------------------------
__global__ __launch_bounds__(256) void pairdist_kernel(
    const float* __restrict__ x, const float* __restrict__ y,
    float* __restrict__ E) {
  const int b  = blockIdx.z;
  const int n0 = blockIdx.x * 64;   // j tile (rows of D')
  const int m0 = blockIdx.y * 64;   // i tile (cols of D')

  __shared__ float xs[TC][64];
  __shared__ float ys[TC][64];
  __shared__ float xxs[64];
  __shared__ float yys[64];

  const float* xb = x + (size_t)b * TC * TN;
  const float* yb = y + (size_t)b * TC * TN;
  const int tid = threadIdx.x;

  for (int idx = tid; idx < TC * 64; idx += 256) {
    int c = idx >> 6, n = idx & 63;
    xs[c][n] = xb[c * TN + n0 + n];
    ys[c][n] = yb[c * TN + m0 + n];
  }
  __syncthreads();

  if (tid < 64) {
    float s = 0.f;
    for (int c = 0; c < TC; ++c) { float v = xs[c][tid]; s += v * v; }
    xxs[tid] = s;
  } else if (tid < 128) {
    int t2 = tid - 64;
    float s = 0.f;
    for (int c = 0; c < TC; ++c) { float v = ys[c][t2]; s += v * v; }
    yys[t2] = s;
  }
  __syncthreads();

  const int tm = tid & 15, tn = tid >> 4;
  float acc[4][4] = {};
  for (int c = 0; c < TC; ++c) {
    float4 xa = *(const float4*)&xs[c][tn * 4];
    float4 ya = *(const float4*)&ys[c][tm * 4];
    float xv[4] = {xa.x, xa.y, xa.z, xa.w};
    float yv[4] = {ya.x, ya.y, ya.z, ya.w};
#pragma unroll
    for (int a = 0; a < 4; ++a)
#pragma unroll
      for (int q = 0; q < 4; ++q) acc[a][q] += xv[a] * yv[q];
  }

  float* Eb = E + (size_t)b * TN * TN;
  const int tE = (m0 >> 3) + (tm >> 1);   // i >> 3
  const int wE = (tm & 1) * 4;            // i & 7 (float4-aligned)
#pragma unroll
  for (int a = 0; a < 4; ++a) {
    int j = n0 + tn * 4 + a;              // row of D'
    float xxv = xxs[tn * 4 + a];
    float4 o;
    o.x = (xxv + yys[tm * 4 + 0] - 2.f * acc[a][0]) * L2E;
    o.y = (xxv + yys[tm * 4 + 1] - 2.f * acc[a][1]) * L2E;
    o.z = (xxv + yys[tm * 4 + 2] - 2.f * acc[a][2]) * L2E;
    o.w = (xxv + yys[tm * 4 + 3] - 2.f * acc[a][3]) * L2E;
    int p = (j + tE) & (TN - 1);
    *(float4*)&Eb[(size_t)p * TN + tE * 8 + wE] = o;
  }
}

// ---------------------------------------------------------------------------
// Kernel 2: soft-DTW single-wave slab sweep, LDS-ring prefetch (depth 8),
// now reading the skewed-contiguous E layout in log2 domain.
//
// Round-4 post-mortem: per-iter 1282 cy; the vmcnt wait was blocked on DMA
// COMPLETION RATE — 64 scattered cache lines per instruction (lane stride
// 2048-32 B). Fix: E layout makes steady-state iterations read ONE
// contiguous 2 KB row (32 sequential lines). Head/tail lanes still use the
// per-lane clamp (global_load_lds sources are per-lane). Everything else —
// 8-slot LDS ring, counted vmcnt(14), atomic ds_read+lgkmcnt(0) asm, DPP
// boundary pass — is the verified round-4 machinery.
//
// Chain shortened via log2-domain softmin: raw v_exp/v_log (no 1/ln2 muls);
// D pre-scaled by log2e in pairdist, output scaled back by ln2. BIG=1e30
// self-sustains bitwise: all-BIG inputs give 1e30 - log2(3) -> 1e30 exact.
// Exactly 575 iterations (71 x 8 + 7 peeled).
// ---------------------------------------------------------------------------
__global__ __launch_bounds__(64) __attribute__((amdgpu_waves_per_eu(1)))
void sdtw_kernel(const float* __restrict__ Et, float* __restrict__ out) {
  const int b = blockIdx.x;
  const int t = threadIdx.x;          // lane, owns rows 8t+1..8t+8
  const float* Eb = Et + (size_t)b * TN * TN;

  __shared__ float ring[8][512];      // 8 slots x 2 KB

  float prev[8];                      // R'[i][j-1] for own 8 rows
#pragma unroll
  for (int r = 0; r < 8; ++r) prev[r] = BIGF;
  float up_cur  = BIGF;               // R'[8t][j]
  float up_prev = (t == 0) ? 0.f : BIGF;  // R'[8t][j-1]; R'[0][0]=0

  // Per-lane pointer to lane t's 8 floats for sweep iteration s:
  // physical row p = (clamp(s-t,0,511)+t) & 511, slot offset t*8.
  // Steady state (63<=s<=511): p == s for all lanes -> contiguous 2 KB.
  auto rowp = [&](int s) -> const float* {
    int v = s - t;
    v = v < 0 ? 0 : (v > TN - 1 ? TN - 1 : v);
    int p = (v + t) & (TN - 1);
    return Eb + (size_t)p * TN + t * 8;
  };

  auto stage = [&](int slot, const float* gp) {
    __builtin_amdgcn_global_load_lds((gu32*)gp,       (lu32*)&ring[slot][0],
                                     16, 0, 0);
    __builtin_amdgcn_global_load_lds((gu32*)(gp + 4), (lu32*)&ring[slot][256],
                                     16, 0, 0);
  };

  const unsigned lbase =
      (unsigned)(size_t)(__attribute__((address_space(3))) float*)&ring[0][0];

  // Preamble: fill all 8 slots (iters 0..7) -> 16 outstanding DMA ops.
  stage(0, rowp(0)); stage(1, rowp(1)); stage(2, rowp(2)); stage(3, rowp(3));
  stage(4, rowp(4)); stage(5, rowp(5)); stage(6, rowp(6)); stage(7, rowp(7));

  auto body = [&](int s, int slot) {
    // Oldest slot's 2 DMA writes have landed in LDS.
    asm volatile("s_waitcnt vmcnt(14)" ::: "memory");

    // Atomic LDS->reg read: lgkmcnt(0) inside the asm -> outputs are
    // complete values at asm exit (no async-register hazard).
    f32x4 cA, cB;
    unsigned a = lbase + (unsigned)(slot * 2048) + (unsigned)(t * 16);
    asm volatile("ds_read_b128 %0, %2\n\t"
                 "ds_read_b128 %1, %2 offset:1024\n\t"
                 "s_waitcnt lgkmcnt(0)"
                 : "=&v"(cA), "=&v"(cB)
                 : "v"(a)
                 : "memory");

    // Refill this slot for iteration s+8.
    stage(slot, rowp(s + 8));

    float dv[8] = {cA[0], cA[1], cA[2], cA[3], cB[0], cB[1], cB[2], cB[3]};
    float r0 = up_prev;               // R'[i-1][j-1]
    float r1 = up_cur;                // R'[i-1][j]
#pragma unroll
    for (int r = 0; r < 8; ++r) {
      float r2 = prev[r];             // R'[i][j-1]
      float m3 = fminf(fminf(r0, r1), r2);
      float ss = __builtin_amdgcn_exp2f(m3 - r0) +
                 __builtin_amdgcn_exp2f(m3 - r1) +
                 __builtin_amdgcn_exp2f(m3 - r2);
      float cur = dv[r] + (m3 - __builtin_amdgcn_logf(ss));
      r0 = r2;
      prev[r] = cur;
      r1 = cur;
    }
    up_prev = up_cur;
    // prev[7] shifted up one lane; lane 0 receives BIG. Pure VALU DPP.
    int sh = __builtin_amdgcn_update_dpp(
        __float_as_int(BIGF), __float_as_int(prev[7]), 0x138, 0xf, 0xf, false);
    up_cur = __int_as_float(sh);
  };

  // 575 total iterations: 71 x 8 unrolled + 7 peeled.
  for (int s = 0; s < 568; s += 8) {
    body(s + 0, 0); body(s + 1, 1); body(s + 2, 2); body(s + 3, 3);
    body(s + 4, 4); body(s + 5, 5); body(s + 6, 6); body(s + 7, 7);
  }
  body(568, 0); body(569, 1); body(570, 2); body(571, 3);
  body(572, 4); body(573, 5); body(574, 6);

  // Drain remaining speculative DMA before wave exit.
  asm volatile("s_waitcnt vmcnt(0)" ::: "memory");
  if (t == 63) out[b] = prev[7] * LN2;   // back to ln-domain
}

extern "C" void kernel_launch(void* const* d_in, const int* in_sizes, int n_in,
                              void* d_out, int out_size, void* d_ws, size_t ws_size,
                              hipStream_t stream) {
  const float* x = (const float*)d_in[0];
  const float* y = (const float*)d_in[1];
  float* out = (float*)d_out;
  float* E = (float*)d_ws;  // 32*512*512*4 = 33.5 MB, skewed layout

  dim3 g1(TN / 64, TN / 64, 32);
  // Swapped args -> values are bitwise D^T, stored skewed + log2e-scaled.
  pairdist_kernel<<<g1, 256, 0, stream>>>(y, x, E);
  sdtw_kernel<<<32, 64, 0, stream>>>(E, out);
}